// Round 1
// baseline (109654.138 us; speedup 1.0000x reference)
//
#include <hip/hip_runtime.h>
#include <stdint.h>

#define Bq   128
#define Tq   2048
#define Dq   512
#define Z0q  64
#define Z1q  32
#define OUTq 64

// ---- bf16 helpers (manual, RNE) ----
__device__ inline float bflo(uint32_t u){ return __uint_as_float(u << 16); }
__device__ inline float bfhi(uint32_t u){ return __uint_as_float(u & 0xffff0000u); }

__device__ inline uint16_t f2bf(float f){
  uint32_t u = __float_as_uint(f);
  u += 0x7fffu + ((u >> 16) & 1u);   // round-to-nearest-even
  return (uint16_t)(u >> 16);
}

// Repack f32 [K][N] row-major -> bf16, k-octet interleaved:
// u32 index q = (k8*N + j)*4 + w holds bf16 pair (k=8*k8+2*w, k+1) for column j.
// A uint4 load at [k8*N + j] then yields 8 consecutive-k weights for column j.
__global__ void repack_bf16(const float* __restrict__ src, uint32_t* __restrict__ dst,
                            int K, int N){
  int q = blockIdx.x * blockDim.x + threadIdx.x;
  int total = (K * N) >> 1;
  if (q >= total) return;
  int w   = q & 3;
  int rem = q >> 2;
  int j   = rem % N;
  int k8  = rem / N;
  int k   = k8 * 8 + w * 2;
  float a = src[(size_t)k * N + j];
  float b = src[(size_t)(k + 1) * N + j];
  dst[q] = (uint32_t)f2bf(a) | ((uint32_t)f2bf(b) << 16);
}

// dot over K of (bf16 weight column j) * (f32 vector in LDS)
template<int K, int N>
__device__ inline float dotp(const uint4* __restrict__ W, const float* __restrict__ dl, int j){
  float a0 = 0.f, a1 = 0.f, a2 = 0.f, a3 = 0.f;
  const uint4* p = W + j;
  #pragma unroll 4
  for (int k8 = 0; k8 < K / 8; ++k8){
    uint4 w = p[(size_t)k8 * N];
    float4 dA = *reinterpret_cast<const float4*>(dl + k8 * 8);
    float4 dB = *reinterpret_cast<const float4*>(dl + k8 * 8 + 4);
    a0 = fmaf(bflo(w.x), dA.x, a0);
    a1 = fmaf(bfhi(w.x), dA.y, a1);
    a2 = fmaf(bflo(w.y), dA.z, a2);
    a3 = fmaf(bfhi(w.y), dA.w, a3);
    a0 = fmaf(bflo(w.z), dB.x, a0);
    a1 = fmaf(bfhi(w.z), dB.y, a1);
    a2 = fmaf(bflo(w.w), dB.z, a2);
    a3 = fmaf(bfhi(w.w), dB.w, a3);
  }
  return (a0 + a1) + (a2 + a3);
}

// One workgroup per batch row; 512 threads; t-loop inside; 3 barriers/step.
__global__ __launch_bounds__(512, 1) void pvrnn_scan(
    const uint4* __restrict__ Wdh0, const uint4* __restrict__ Wzh0,
    const uint4* __restrict__ Wmup0, const uint4* __restrict__ Wsgp0,
    const uint4* __restrict__ Wdh1, const uint4* __restrict__ Wzh1,
    const uint4* __restrict__ Wih1, const uint4* __restrict__ Wmup1,
    const uint4* __restrict__ Wsgp1, const uint4* __restrict__ Wout,
    const float* __restrict__ bh0, const float* __restrict__ bmup0, const float* __restrict__ bsgp0,
    const float* __restrict__ bh1, const float* __restrict__ bmup1, const float* __restrict__ bsgp1,
    const float* __restrict__ bout,
    const float* __restrict__ Amu0, const float* __restrict__ Asg0, const float* __restrict__ Eps0,
    const float* __restrict__ Amu1, const float* __restrict__ Asg1, const float* __restrict__ Eps1,
    float* __restrict__ xout, float* __restrict__ klpart)
{
  const int b = blockIdx.x;
  const int tid = threadIdx.x;

  __shared__ __align__(16) float d0buf[2][Dq];
  __shared__ __align__(16) float d1buf[2][Dq];
  __shared__ __align__(16) float z0s[Z0q], z1s[Z1q];
  __shared__ float muq0s[Z0q], tq0s[Z0q], mup0s[Z0q], tp0s[Z0q];
  __shared__ float muq1s[Z1q], tq1s[Z1q], mup1s[Z1q], tp1s[Z1q];
  __shared__ float red[512];

  d0buf[0][tid] = 0.f; d0buf[1][tid] = 0.f;
  d1buf[0][tid] = 0.f; d1buf[1][tid] = 0.f;

  float h0 = 0.f, h1 = 0.f;
  const float bh0r = bh0[tid];
  const float bh1r = bh1[tid];
  float baux = 0.f;                       // bias for this thread's small-head column
  if      (tid < 64)  baux = bmup0[tid];
  else if (tid < 128) baux = bsgp0[tid - 64];
  else if (tid < 160) baux = bmup1[tid - 128];
  else if (tid < 192) baux = bsgp1[tid - 160];
  const float bor = (tid < OUTq) ? bout[tid] : 0.f;

  float kl0acc = 0.f, kl1acc = 0.f;

  const float* Am0 = Amu0 + (size_t)b * Tq * Z0q;
  const float* As0 = Asg0 + (size_t)b * Tq * Z0q;
  const float* E0  = Eps0 + (size_t)b * Tq * Z0q;
  const float* Am1 = Amu1 + (size_t)b * Tq * Z1q;
  const float* As1 = Asg1 + (size_t)b * Tq * Z1q;
  const float* E1  = Eps1 + (size_t)b * Tq * Z1q;
  float* xo = xout + (size_t)b * Tq * OUTq;

  __syncthreads();

  for (int t = 0; t < Tq; ++t){
    const int cur = t & 1, nxt = cur ^ 1;

    // ---- phase A: posterior stats + z (input-only) ----
    if (tid < Z0q){
      float am = Am0[(size_t)t * Z0q + tid];
      float as = As0[(size_t)t * Z0q + tid];
      float e  = E0 [(size_t)t * Z0q + tid];
      float mq = tanhf(am), tqv = tanhf(as);
      muq0s[tid] = mq; tq0s[tid] = tqv;          // tq = log(sgq)
      z0s[tid] = fmaf(__expf(tqv), e, mq);
    } else if (tid < Z0q + Z1q){
      int i = tid - Z0q;
      float am = Am1[(size_t)t * Z1q + i];
      float as = As1[(size_t)t * Z1q + i];
      float e  = E1 [(size_t)t * Z1q + i];
      float mq = tanhf(am), tqv = tanhf(as);
      muq1s[i] = mq; tq1s[i] = tqv;
      z1s[i] = fmaf(__expf(tqv), e, mq);
    }
    __syncthreads();

    // ---- phase B: prior heads (old d) + layer-0 recurrence ----
    const float* d0c = d0buf[cur];
    const float* d1c = d1buf[cur];
    if (tid < 64){
      mup0s[tid]       = tanhf(dotp<Dq, Z0q>(Wmup0, d0c, tid) + baux);
    } else if (tid < 128){
      tp0s[tid - 64]   = tanhf(dotp<Dq, Z0q>(Wsgp0, d0c, tid - 64) + baux);   // tp = log(sgp)
    } else if (tid < 160){
      mup1s[tid - 128] = tanhf(dotp<Dq, Z1q>(Wmup1, d1c, tid - 128) + baux);
    } else if (tid < 192){
      tp1s[tid - 160]  = tanhf(dotp<Dq, Z1q>(Wsgp1, d1c, tid - 160) + baux);
    }
    float acc0 = dotp<Dq, Dq>(Wdh0, d0c, tid) + dotp<Z0q, Dq>(Wzh0, z0s, tid) + bh0r;
    h0 = 0.5f * h0 + 0.5f * acc0;                       // TAU0 = 2
    d0buf[nxt][tid] = tanhf(h0);
    __syncthreads();

    // ---- phase C: KL accumulate + layer-1 recurrence (uses fresh d0n) ----
    if (tid < Z0q){
      float dm = muq0s[tid] - mup0s[tid];
      float tp = tp0s[tid], tqv = tq0s[tid];
      kl0acc += tp - tqv + (__expf(2.f * tqv) + dm * dm) * 0.5f * __expf(-2.f * tp) - 0.5f;
    } else if (tid >= 128 && tid < 128 + Z1q){
      int i = tid - 128;
      float dm = muq1s[i] - mup1s[i];
      float tp = tp1s[i], tqv = tq1s[i];
      kl1acc += tp - tqv + (__expf(2.f * tqv) + dm * dm) * 0.5f * __expf(-2.f * tp) - 0.5f;
    }
    const float* d0n = d0buf[nxt];
    float acc1 = dotp<Dq, Dq>(Wdh1, d1c, tid) + dotp<Dq, Dq>(Wih1, d0n, tid)
               + dotp<Z1q, Dq>(Wzh1, z1s, tid) + bh1r;
    h1 = 0.875f * h1 + 0.125f * acc1;                   // TAU1 = 8
    d1buf[nxt][tid] = tanhf(h1);
    __syncthreads();

    // ---- phase D: output head (no trailing barrier needed) ----
    if (tid < OUTq){
      float acc2 = dotp<Dq, OUTq>(Wout, d1buf[nxt], tid) + bor;
      xo[(size_t)t * OUTq + tid] = 1.f / (1.f + __expf(-acc2));
    }
  }

  // ---- per-row KL partials ----
  red[tid] = kl0acc; __syncthreads();
  for (int s = 256; s > 0; s >>= 1){ if (tid < s) red[tid] += red[tid + s]; __syncthreads(); }
  float k0 = red[0];
  __syncthreads();
  red[tid] = kl1acc; __syncthreads();
  for (int s = 256; s > 0; s >>= 1){ if (tid < s) red[tid] += red[tid + s]; __syncthreads(); }
  if (tid == 0){ klpart[b] = k0; klpart[Bq + b] = red[0]; }
}

__global__ void kl_finalize(const float* __restrict__ klpart, float* __restrict__ out){
  if (blockIdx.x == 0 && threadIdx.x == 0){
    float k0 = 0.f, k1 = 0.f;
    for (int i = 0; i < Bq; ++i){ k0 += klpart[i]; k1 += klpart[Bq + i]; }
    out[(size_t)Bq * Tq * OUTq]     = (k0 + k1) * (1.0f / Bq);
    out[(size_t)Bq * Tq * OUTq + 1] = (0.001f * k0 + 0.001f * k1) * (1.0f / Bq);
  }
}

extern "C" void kernel_launch(void* const* d_in, const int* in_sizes, int n_in,
                              void* d_out, int out_size, void* d_ws, size_t ws_size,
                              hipStream_t stream) {
  const float* Wdh0  = (const float*)d_in[0];
  const float* Wzh0  = (const float*)d_in[1];
  const float* bh0   = (const float*)d_in[2];
  const float* Wmup0 = (const float*)d_in[3];
  const float* bmup0 = (const float*)d_in[4];
  const float* Wsgp0 = (const float*)d_in[5];
  const float* bsgp0 = (const float*)d_in[6];
  const float* Amu0  = (const float*)d_in[7];
  const float* Asg0  = (const float*)d_in[8];
  const float* Eps0  = (const float*)d_in[9];
  const float* Wdh1  = (const float*)d_in[10];
  const float* Wzh1  = (const float*)d_in[11];
  const float* Wih1  = (const float*)d_in[12];
  const float* bh1   = (const float*)d_in[13];
  const float* Wmup1 = (const float*)d_in[14];
  const float* bmup1 = (const float*)d_in[15];
  const float* Wsgp1 = (const float*)d_in[16];
  const float* bsgp1 = (const float*)d_in[17];
  const float* Amu1  = (const float*)d_in[18];
  const float* Asg1  = (const float*)d_in[19];
  const float* Eps1  = (const float*)d_in[20];
  const float* Wout  = (const float*)d_in[21];
  const float* bout  = (const float*)d_in[22];

  uint32_t* ws = (uint32_t*)d_ws;
  size_t off = 0;
  auto alloc = [&](size_t n){ size_t o = off; off += n; return o; };
  const size_t oWdh0  = alloc(131072);
  const size_t oWzh0  = alloc(16384);
  const size_t oWmup0 = alloc(16384);
  const size_t oWsgp0 = alloc(16384);
  const size_t oWdh1  = alloc(131072);
  const size_t oWzh1  = alloc(8192);
  const size_t oWih1  = alloc(131072);
  const size_t oWmup1 = alloc(8192);
  const size_t oWsgp1 = alloc(8192);
  const size_t oWout  = alloc(16384);
  const size_t oKL    = alloc(256);
  if (ws_size < off * sizeof(uint32_t)) return;  // fail loud rather than corrupt

  auto rp = [&](const float* src, size_t o, int K, int N){
    int total = (K * N) >> 1;
    repack_bf16<<<(total + 255) / 256, 256, 0, stream>>>(src, ws + o, K, N);
  };
  rp(Wdh0,  oWdh0,  512, 512);
  rp(Wzh0,  oWzh0,  64,  512);
  rp(Wmup0, oWmup0, 512, 64);
  rp(Wsgp0, oWsgp0, 512, 64);
  rp(Wdh1,  oWdh1,  512, 512);
  rp(Wzh1,  oWzh1,  32,  512);
  rp(Wih1,  oWih1,  512, 512);
  rp(Wmup1, oWmup1, 512, 32);
  rp(Wsgp1, oWsgp1, 512, 32);
  rp(Wout,  oWout,  512, 64);

  float* xout = (float*)d_out;
  pvrnn_scan<<<Bq, 512, 0, stream>>>(
      (const uint4*)(ws + oWdh0),  (const uint4*)(ws + oWzh0),
      (const uint4*)(ws + oWmup0), (const uint4*)(ws + oWsgp0),
      (const uint4*)(ws + oWdh1),  (const uint4*)(ws + oWzh1),
      (const uint4*)(ws + oWih1),  (const uint4*)(ws + oWmup1),
      (const uint4*)(ws + oWsgp1), (const uint4*)(ws + oWout),
      bh0, bmup0, bsgp0, bh1, bmup1, bsgp1, bout,
      Amu0, Asg0, Eps0, Amu1, Asg1, Eps1,
      xout, (float*)(ws + oKL));

  kl_finalize<<<1, 64, 0, stream>>>((const float*)(ws + oKL), xout);
}

// Round 2
// 31345.700 us; speedup vs baseline: 3.4982x; 3.4982x over previous
//
#include <hip/hip_runtime.h>
#include <stdint.h>

typedef float  f32x4  __attribute__((ext_vector_type(4)));
typedef short  short8 __attribute__((ext_vector_type(8)));

__device__ inline uint16_t f2bf(float f){
  uint32_t u = __float_as_uint(f);
  u += 0x7fffu + ((u >> 16) & 1u);   // RNE
  return (uint16_t)(u >> 16);
}

// ---------------- prepack: weights -> per-WG MFMA B-fragment records ----------------
// record = 1KB: 64 lanes x 16B; lane l holds W[kbase+(l>>4)*8+j][colbase+(l&15)], j=0..7
// L0 slice s (52 recs): [0..47] combined(Wdh0|mup0|sgp0|pad) n=0..2,k=0..15 ; [48..51] Wzh0 n=0..1,k=0..1
// L1 slice s (82 recs): [0..47] combined(Wdh1|mup1|sgp1|Wout|pad) ; [48..79] Wih1 n=0..1,k=0..15 ; [80..81] Wzh1

struct PreP {
  const float *Wdh0,*Wzh0,*Wmup0,*Wsgp0,*Wdh1,*Wzh1,*Wih1,*Wmup1,*Wsgp1,*Wout;
  uint32_t* dst;
};

__global__ __launch_bounds__(64) void prepack(PreP P){
  const int rec = blockIdx.x, l = threadIdx.x;
  int role, s, r;
  if (rec < 832){ role = 0; s = rec / 52; r = rec % 52; }
  else          { role = 1; int rr = rec - 832; s = rr / 82; r = rr % 82; }
  const int cl = l & 15, kb = (l >> 4) * 8;
  float v[8];
#pragma unroll
  for (int j = 0; j < 8; ++j) v[j] = 0.f;
  if (role == 0){
    if (r < 48){
      int n = r >> 4, k = r & 15, c = 16*n + cl, kk0 = k*32 + kb;
      if (c < 32){ int col = 32*s + c;
#pragma unroll
        for (int j = 0; j < 8; ++j) v[j] = P.Wdh0[(size_t)(kk0+j)*512 + col];
      } else if (c < 36){ int col = 4*s + (c-32);
#pragma unroll
        for (int j = 0; j < 8; ++j) v[j] = P.Wmup0[(size_t)(kk0+j)*64 + col];
      } else if (c < 40){ int col = 4*s + (c-36);
#pragma unroll
        for (int j = 0; j < 8; ++j) v[j] = P.Wsgp0[(size_t)(kk0+j)*64 + col];
      }
    } else {
      int r2 = r - 48, n = r2 >> 1, k = r2 & 1, col = 32*s + 16*n + cl, kk0 = k*32 + kb;
#pragma unroll
      for (int j = 0; j < 8; ++j) v[j] = P.Wzh0[(size_t)(kk0+j)*512 + col];
    }
  } else {
    if (r < 48){
      int n = r >> 4, k = r & 15, c = 16*n + cl, kk0 = k*32 + kb;
      if (c < 32){ int col = 32*s + c;
#pragma unroll
        for (int j = 0; j < 8; ++j) v[j] = P.Wdh1[(size_t)(kk0+j)*512 + col];
      } else if (c < 34){ int col = 2*s + (c-32);
#pragma unroll
        for (int j = 0; j < 8; ++j) v[j] = P.Wmup1[(size_t)(kk0+j)*32 + col];
      } else if (c < 36){ int col = 2*s + (c-34);
#pragma unroll
        for (int j = 0; j < 8; ++j) v[j] = P.Wsgp1[(size_t)(kk0+j)*32 + col];
      } else if (c < 40){ int col = 4*s + (c-36);
#pragma unroll
        for (int j = 0; j < 8; ++j) v[j] = P.Wout[(size_t)(kk0+j)*64 + col];
      }
    } else if (r < 80){
      int r2 = r - 48, n = r2 >> 4, k = r2 & 15, col = 32*s + 16*n + cl, kk0 = k*32 + kb;
#pragma unroll
      for (int j = 0; j < 8; ++j) v[j] = P.Wih1[(size_t)(kk0+j)*512 + col];
    } else {
      int n = r - 80, col = 32*s + 16*n + cl;
#pragma unroll
      for (int j = 0; j < 8; ++j) v[j] = P.Wzh1[(size_t)(kb+j)*512 + col];
    }
  }
  uint32_t o0 = (uint32_t)f2bf(v[0]) | ((uint32_t)f2bf(v[1]) << 16);
  uint32_t o1 = (uint32_t)f2bf(v[2]) | ((uint32_t)f2bf(v[3]) << 16);
  uint32_t o2 = (uint32_t)f2bf(v[4]) | ((uint32_t)f2bf(v[5]) << 16);
  uint32_t o3 = (uint32_t)f2bf(v[6]) | ((uint32_t)f2bf(v[7]) << 16);
  ((uint4*)(P.dst + (size_t)rec * 256))[l] = make_uint4(o0, o1, o2, o3);
}

// ---------------- cooperative pipelined scan ----------------
// 4 row-groups (32 batch rows each) x (16 L0-slice WGs + 16 L1-slice WGs) = 128 WGs, 384 thr.
// L0 WG at step t: d0(t) slice from d0(t-1) [pub0 ring] + z0(t). Publishes pub0[t&3], flags ctrA[t].
// L1 WG at step t: d1(t) slice from d1(t-1), d0(t), z1(t); also mup1/sgp1 (KL) and x(t-1). Flags ctrB[t].

struct ScanP {
  const short* wrec;
  short *pub0, *pub1;
  int *ctrA, *ctrB;
  const float *bh0,*bmup0,*bsgp0,*bh1,*bmup1,*bsgp1,*bout;
  const float *Am0,*As0,*E0,*Am1,*As1,*E1;
  float *out, *klpart;
};

__global__ __launch_bounds__(384, 1) void pvrnn_scan(ScanP P){
  extern __shared__ char smem[];
  short* ldsW  = (short*)smem;                   // up to 82 records * 1024B
  float* muqS  = (float*)(smem + 83968);         // [2][32][64] f32
  float* tqS   = (float*)(smem + 100352);        // [2][32][64] f32
  short* zbS   = (short*)(smem + 116736);        // [2][32][CW] bf16
  short* dtile = (short*)(smem + 124928);        // [32][32] bf16
  float* mupT  = (float*)(smem + 126976);        // [32][4]
  float* tpT   = (float*)(smem + 127488);        // [32][4]
  float* xT    = (float*)(smem + 128000);        // [32][4]

  const int p = blockIdx.x;
  const int xcd = p & 7;
  const int g = xcd >> 1;                         // group co-located on 2 XCDs
  const int r5 = ((p >> 3) << 1) | (xcd & 1);     // 0..31
  const int role = (r5 >> 4) & 1;                 // 0=L0, 1=L1
  const int s = r5 & 15;                          // slice
  const int wid = g*32 + role*16 + s;

  const int tid = threadIdx.x;
  const int l = tid & 63, w = tid >> 6;           // wave 0..5
  const int m = w & 1, n = w >> 1;                // n: 0,1 rec ; 2 head
  const int c = l & 15, kb8 = (l >> 4) * 8;
  const int rowbase = 32*g + 16*m;
  const int CW = role ? 32 : 64;
  const int sh = role ? 5 : 6;

  { // weights -> LDS (linear, conflict-free records)
    const uint4* src = (const uint4*)(P.wrec + (size_t)(role ? (832 + s*82) : (s*52)) * 512);
    const int n16 = (role ? 82 : 52) * 64;
    for (int i = tid; i < n16; i += 384) ((uint4*)ldsW)[i] = src[i];
  }
  float bias_rec = 0.f, bias_head = 0.f;
  if (n < 2){
    bias_rec = role ? P.bh1[32*s + 16*n + c] : P.bh0[32*s + 16*n + c];
  } else {
    if (!role){
      if (c < 4)      bias_head = P.bmup0[4*s + c];
      else if (c < 8) bias_head = P.bsgp0[4*s + c - 4];
    } else {
      if (c < 2)      bias_head = P.bmup1[2*s + c];
      else if (c < 4) bias_head = P.bsgp1[2*s + c - 2];
      else if (c < 8) bias_head = P.bout [4*s + c - 4];
    }
  }
  const float* AM = role ? P.Am1 : P.Am0;
  const float* AS = role ? P.As1 : P.As0;
  const float* EP = role ? P.E1  : P.E0;

  auto do_stats = [&](int tt){
    const int par2 = tt & 1;
    const int NE = 32 << sh;
    for (int idx = tid; idx < NE; idx += 384){
      int rr = idx >> sh, cc = idx & (CW - 1);
      size_t sidx = ((size_t)(32*g + rr) * 2048 + tt) * CW + cc;
      float mq = tanhf(AM[sidx]);
      float tq = tanhf(AS[sidx]);
      int o = (par2*32 + rr)*64 + cc;
      muqS[o] = mq; tqS[o] = tq;
      zbS[(par2*32 + rr)*CW + cc] = (short)f2bf(fmaf(__expf(tq), EP[sidx], mq));
    }
  };
  do_stats(0);
  __syncthreads();

  float h[4] = {0.f,0.f,0.f,0.f};
  float klacc = 0.f;
  bool dead = false;
  int* myctr  = (role ? P.ctrB : P.ctrA) + g * 2052;
  int* othctr = (role ? P.ctrA : P.ctrB) + g * 2052;
  const short* pubA = role ? P.pub1 : P.pub0;
  short* pubW = role ? P.pub1 : P.pub0;
  const float leak = role ? 0.875f : 0.5f, gain = role ? 0.125f : 0.5f;

  for (int t = 0; t < 2048; ++t){
    if (tid == 0){
      auto spinw = [&](int* a, int tgt){
        if (dead) return;
        int it = 0;
        while (atomicAdd(a, 0) < tgt){            // coherent RMW poll
          __builtin_amdgcn_s_sleep(2);
          if (++it > 5000000){ dead = true; return; }
        }
      };
      if (!role){
        if (t >= 1) spinw(myctr + (t-1), 16);     // own layer chain
        if (t >= 4) spinw(othctr + (t-4), 16);    // ring overwrite safety
      } else {
        spinw(othctr + t, 16);                    // d0(t) ready
        if (t >= 1) spinw(myctr + (t-1), 16);     // d1(t-1) ready
      }
      __threadfence();                            // acquire: inv L1/L2
    }
    __syncthreads();

    const int par = t & 1;
    const short* A1 = pubA + (size_t)(((t-1)&3)*128 + rowbase) * 512;
    short8 af[16];
#pragma unroll
    for (int k = 0; k < 16; ++k)
      af[k] = *(const short8*)(A1 + c*512 + k*32 + kb8);
    f32x4 acc = {0.f,0.f,0.f,0.f};
#pragma unroll
    for (int k = 0; k < 16; ++k){
      short8 bf = *(const short8*)(ldsW + (n*16 + k)*512 + l*8);
      acc = __builtin_amdgcn_mfma_f32_16x16x32_bf16(af[k], bf, acc, 0, 0, 0);
    }
    if (n < 2){
      if (role){
        const short* A2 = P.pub0 + (size_t)((t&3)*128 + rowbase) * 512;
#pragma unroll
        for (int k = 0; k < 16; ++k){
          short8 a2 = *(const short8*)(A2 + c*512 + k*32 + kb8);
          short8 bf = *(const short8*)(ldsW + (48 + n*16 + k)*512 + l*8);
          acc = __builtin_amdgcn_mfma_f32_16x16x32_bf16(a2, bf, acc, 0, 0, 0);
        }
        short8 az = *(const short8*)(zbS + (par*32 + 16*m + c)*32 + kb8);
        short8 bz = *(const short8*)(ldsW + (80 + n)*512 + l*8);
        acc = __builtin_amdgcn_mfma_f32_16x16x32_bf16(az, bz, acc, 0, 0, 0);
      } else {
#pragma unroll
        for (int kk = 0; kk < 2; ++kk){
          short8 az = *(const short8*)(zbS + (par*32 + 16*m + c)*64 + kk*32 + kb8);
          short8 bz = *(const short8*)(ldsW + (48 + n*2 + kk)*512 + l*8);
          acc = __builtin_amdgcn_mfma_f32_16x16x32_bf16(az, bz, acc, 0, 0, 0);
        }
      }
    }
    // epilogue
    if (n < 2){
#pragma unroll
      for (int j = 0; j < 4; ++j){
        float pre = acc[j] + bias_rec;
        h[j] = leak*h[j] + gain*pre;
        int row = 16*m + (l>>4)*4 + j;
        dtile[row*32 + 16*n + c] = (short)f2bf(tanhf(h[j]));
      }
    } else {
#pragma unroll
      for (int j = 0; j < 4; ++j){
        float pre = acc[j] + bias_head;
        int row = 16*m + (l>>4)*4 + j;
        if (!role){
          if (c < 4)      mupT[row*4 + c]     = tanhf(pre);
          else if (c < 8) tpT [row*4 + c - 4] = tanhf(pre);
        } else {
          if (c < 2)      mupT[row*4 + c]     = tanhf(pre);
          else if (c < 4) tpT [row*4 + c - 2] = tanhf(pre);
          else if (c < 8) xT  [row*4 + c - 4] = 1.f/(1.f + __expf(-pre));
        }
      }
    }
    __syncthreads();
    if (w < 2){                                   // publish d slice (coalesced 64B rows)
      int row = tid >> 2, qq = tid & 3;
      *(uint4*)(pubW + (size_t)((t&3)*128 + 32*g + row)*512 + 32*s + qq*8)
        = *(const uint4*)(dtile + row*32 + qq*8);
    } else if (w == 2 && l < 32){
      if (role && t >= 1)
        *(float4*)(P.out + ((size_t)(32*g + l)*2048 + (t-1))*64 + 4*s)
          = *(const float4*)(xT + l*4);
    } else if (w == 4 && l < 32){
      const int CC = role ? 2 : 4;
#pragma unroll
      for (int cc = 0; cc < 4; ++cc){
        if (cc < CC){
          float mp = mupT[l*4 + cc], tp = tpT[l*4 + cc];
          int zc = role ? (2*s + cc) : (4*s + cc);
          float mq = muqS[(par*32 + l)*64 + zc];
          float tq = tqS [(par*32 + l)*64 + zc];
          float dm = mq - mp;
          klacc += tp - tq + (__expf(2.f*tq) + dm*dm)*0.5f*__expf(-2.f*tp) - 0.5f;
        }
      }
    }
    __syncthreads();                              // drains pub stores (vmcnt before barrier)
    if (tid == 0){
      __threadfence();                            // release: wb L2 -> LLC
      atomicAdd(myctr + t, 1);
    }
    if (t + 1 < 2048) do_stats(t + 1);            // overlap next-step input stats
  }

  if (role){                                      // final x(2047) from d1(2047)
    if (tid == 0){
      int it = 0;
      while (!dead && atomicAdd(myctr + 2047, 0) < 16){
        __builtin_amdgcn_s_sleep(2);
        if (++it > 5000000) dead = true;
      }
      __threadfence();
    }
    __syncthreads();
    if (n == 2){
      const short* A1 = P.pub1 + (size_t)((2047&3)*128 + rowbase) * 512;
      f32x4 acc = {0.f,0.f,0.f,0.f};
#pragma unroll
      for (int k = 0; k < 16; ++k){
        short8 a  = *(const short8*)(A1 + c*512 + k*32 + kb8);
        short8 bf = *(const short8*)(ldsW + (32 + k)*512 + l*8);
        acc = __builtin_amdgcn_mfma_f32_16x16x32_bf16(a, bf, acc, 0, 0, 0);
      }
#pragma unroll
      for (int j = 0; j < 4; ++j){
        if (c >= 4 && c < 8){
          int row = 16*m + (l>>4)*4 + j;
          xT[row*4 + c - 4] = 1.f/(1.f + __expf(-(acc[j] + bias_head)));
        }
      }
    }
    __syncthreads();
    if (w == 2 && l < 32)
      *(float4*)(P.out + ((size_t)(32*g + l)*2048 + 2047)*64 + 4*s)
        = *(const float4*)(xT + l*4);
  }

  if (w == 4){
    float v = klacc;
#pragma unroll
    for (int off = 32; off; off >>= 1) v += __shfl_down(v, off);
    if (l == 0) P.klpart[wid] = v;
  }
}

__global__ void kl_finalize(const float* __restrict__ klpart, float* __restrict__ out){
  if (blockIdx.x == 0 && threadIdx.x == 0){
    float k0 = 0.f, k1 = 0.f;
    for (int i = 0; i < 128; ++i){
      if ((i >> 4) & 1) k1 += klpart[i]; else k0 += klpart[i];
    }
    float kl = (k0 + k1) * (1.0f/128.0f);
    out[16777216] = kl;
    out[16777217] = 0.001f * kl;
  }
}

extern "C" void kernel_launch(void* const* d_in, const int* in_sizes, int n_in,
                              void* d_out, int out_size, void* d_ws, size_t ws_size,
                              hipStream_t stream){
  (void)in_sizes; (void)n_in; (void)out_size;
  const float* Wdh0  = (const float*)d_in[0];
  const float* Wzh0  = (const float*)d_in[1];
  const float* bh0   = (const float*)d_in[2];
  const float* Wmup0 = (const float*)d_in[3];
  const float* bmup0 = (const float*)d_in[4];
  const float* Wsgp0 = (const float*)d_in[5];
  const float* bsgp0 = (const float*)d_in[6];
  const float* Amu0  = (const float*)d_in[7];
  const float* Asg0  = (const float*)d_in[8];
  const float* Eps0  = (const float*)d_in[9];
  const float* Wdh1  = (const float*)d_in[10];
  const float* Wzh1  = (const float*)d_in[11];
  const float* Wih1  = (const float*)d_in[12];
  const float* bh1   = (const float*)d_in[13];
  const float* Wmup1 = (const float*)d_in[14];
  const float* bmup1 = (const float*)d_in[15];
  const float* Wsgp1 = (const float*)d_in[16];
  const float* bsgp1 = (const float*)d_in[17];
  const float* Amu1  = (const float*)d_in[18];
  const float* Asg1  = (const float*)d_in[19];
  const float* Eps1  = (const float*)d_in[20];
  const float* Wout  = (const float*)d_in[21];
  const float* bout  = (const float*)d_in[22];

  // ws layout (bytes)
  const size_t oW    = 0;                      // 2144 records * 1024
  const size_t oPub0 = 2195456;                // [4][128][512] bf16
  const size_t oPub1 = oPub0 + 524288;
  const size_t oCtrA = oPub1 + 524288;         // 4 groups * 2052 ints
  const size_t oCtrB = oCtrA + 32832;
  const size_t oKL   = oCtrB + 32832;
  const size_t total = oKL + 512;
  if (ws_size < total) return;
  char* ws = (char*)d_ws;

  hipMemsetAsync(ws + oPub0, 0, total - oPub0, stream);   // zero pubs + counters + klpart

  PreP pp;
  pp.Wdh0 = Wdh0; pp.Wzh0 = Wzh0; pp.Wmup0 = Wmup0; pp.Wsgp0 = Wsgp0;
  pp.Wdh1 = Wdh1; pp.Wzh1 = Wzh1; pp.Wih1 = Wih1; pp.Wmup1 = Wmup1;
  pp.Wsgp1 = Wsgp1; pp.Wout = Wout; pp.dst = (uint32_t*)(ws + oW);
  prepack<<<dim3(2144), dim3(64), 0, stream>>>(pp);

  ScanP sp;
  sp.wrec = (const short*)(ws + oW);
  sp.pub0 = (short*)(ws + oPub0);
  sp.pub1 = (short*)(ws + oPub1);
  sp.ctrA = (int*)(ws + oCtrA);
  sp.ctrB = (int*)(ws + oCtrB);
  sp.bh0 = bh0; sp.bmup0 = bmup0; sp.bsgp0 = bsgp0;
  sp.bh1 = bh1; sp.bmup1 = bmup1; sp.bsgp1 = bsgp1; sp.bout = bout;
  sp.Am0 = Amu0; sp.As0 = Asg0; sp.E0 = Eps0;
  sp.Am1 = Amu1; sp.As1 = Asg1; sp.E1 = Eps1;
  sp.out = (float*)d_out;
  sp.klpart = (float*)(ws + oKL);

  const unsigned SMEM = 128512u;
  hipFuncSetAttribute((const void*)pvrnn_scan,
                      hipFuncAttributeMaxDynamicSharedMemorySize, 131072);
  void* args[] = { &sp };
  if (hipLaunchCooperativeKernel((void*)pvrnn_scan, dim3(128), dim3(384),
                                 args, SMEM, stream) != hipSuccess){
    // co-residency is guaranteed in practice (128 blocks, 1/CU, empty device)
    pvrnn_scan<<<dim3(128), dim3(384), SMEM, stream>>>(sp);
  }
  kl_finalize<<<1, 1, 0, stream>>>((const float*)(ws + oKL), (float*)d_out);
}

// Round 7
// 25175.984 us; speedup vs baseline: 4.3555x; 1.2451x over previous
//
#include <hip/hip_runtime.h>
#include <stdint.h>

typedef float    f32x4  __attribute__((ext_vector_type(4)));
typedef short    short8 __attribute__((ext_vector_type(8)));
typedef uint32_t u32x4  __attribute__((ext_vector_type(4)));

__device__ inline uint16_t f2bf(float f){
  uint32_t u = __float_as_uint(f);
  u += 0x7fffu + ((u >> 16) & 1u);   // RNE
  return (uint16_t)(u >> 16);
}

// ---------------- prepack: weights -> per-WG MFMA B-fragment records ----------------
// record = 1KB: 64 lanes x 16B; lane l holds W[kbase+(l>>4)*8+j][colbase+(l&15)], j=0..7
struct PreP {
  const float *Wdh0,*Wzh0,*Wmup0,*Wsgp0,*Wdh1,*Wzh1,*Wih1,*Wmup1,*Wsgp1,*Wout;
  uint32_t* dst;
};

__global__ __launch_bounds__(64) void prepack(PreP P){
  const int rec = blockIdx.x, l = threadIdx.x;
  int role, s, r;
  if (rec < 832){ role = 0; s = rec / 52; r = rec % 52; }
  else          { role = 1; int rr = rec - 832; s = rr / 82; r = rr % 82; }
  const int cl = l & 15, kb = (l >> 4) * 8;
  float v[8];
#pragma unroll
  for (int j = 0; j < 8; ++j) v[j] = 0.f;
  if (role == 0){
    if (r < 48){
      int n = r >> 4, k = r & 15, c = 16*n + cl, kk0 = k*32 + kb;
      if (c < 32){ int col = 32*s + c;
#pragma unroll
        for (int j = 0; j < 8; ++j) v[j] = P.Wdh0[(size_t)(kk0+j)*512 + col];
      } else if (c < 36){ int col = 4*s + (c-32);
#pragma unroll
        for (int j = 0; j < 8; ++j) v[j] = P.Wmup0[(size_t)(kk0+j)*64 + col];
      } else if (c < 40){ int col = 4*s + (c-36);
#pragma unroll
        for (int j = 0; j < 8; ++j) v[j] = P.Wsgp0[(size_t)(kk0+j)*64 + col];
      }
    } else {
      int r2 = r - 48, n = r2 >> 1, k = r2 & 1, col = 32*s + 16*n + cl, kk0 = k*32 + kb;
#pragma unroll
      for (int j = 0; j < 8; ++j) v[j] = P.Wzh0[(size_t)(kk0+j)*512 + col];
    }
  } else {
    if (r < 48){
      int n = r >> 4, k = r & 15, c = 16*n + cl, kk0 = k*32 + kb;
      if (c < 32){ int col = 32*s + c;
#pragma unroll
        for (int j = 0; j < 8; ++j) v[j] = P.Wdh1[(size_t)(kk0+j)*512 + col];
      } else if (c < 34){ int col = 2*s + (c-32);
#pragma unroll
        for (int j = 0; j < 8; ++j) v[j] = P.Wmup1[(size_t)(kk0+j)*32 + col];
      } else if (c < 36){ int col = 2*s + (c-34);
#pragma unroll
        for (int j = 0; j < 8; ++j) v[j] = P.Wsgp1[(size_t)(kk0+j)*32 + col];
      } else if (c < 40){ int col = 4*s + (c-36);
#pragma unroll
        for (int j = 0; j < 8; ++j) v[j] = P.Wout[(size_t)(kk0+j)*64 + col];
      }
    } else if (r < 80){
      int r2 = r - 48, n = r2 >> 4, k = r2 & 15, col = 32*s + 16*n + cl, kk0 = k*32 + kb;
#pragma unroll
      for (int j = 0; j < 8; ++j) v[j] = P.Wih1[(size_t)(kk0+j)*512 + col];
    } else {
      int n = r - 80, col = 32*s + 16*n + cl;
#pragma unroll
      for (int j = 0; j < 8; ++j) v[j] = P.Wzh1[(size_t)(kb+j)*512 + col];
    }
  }
  u32x4 o;
  o.x = (uint32_t)f2bf(v[0]) | ((uint32_t)f2bf(v[1]) << 16);
  o.y = (uint32_t)f2bf(v[2]) | ((uint32_t)f2bf(v[3]) << 16);
  o.z = (uint32_t)f2bf(v[4]) | ((uint32_t)f2bf(v[5]) << 16);
  o.w = (uint32_t)f2bf(v[6]) | ((uint32_t)f2bf(v[7]) << 16);
  ((u32x4*)(P.dst + (size_t)rec * 256))[l] = o;
}

// ---- device-coherent (LLC) transport helpers: no L2 flush/invalidate ----
__device__ inline void gld16(u32x4 (&a)[16], const short* base){
#define GLD1(i, OFF) asm volatile("global_load_dwordx4 %0, %1, off offset:" #OFF " sc0 sc1" \
                                  : "=v"(a[i]) : "v"(base) : "memory");
  GLD1(0,0)   GLD1(1,64)  GLD1(2,128) GLD1(3,192)
  GLD1(4,256) GLD1(5,320) GLD1(6,384) GLD1(7,448)
  GLD1(8,512) GLD1(9,576) GLD1(10,640) GLD1(11,704)
  GLD1(12,768) GLD1(13,832) GLD1(14,896) GLD1(15,960)
#undef GLD1
}
__device__ inline void llc_store16(short* dst, u32x4 v){
  asm volatile("global_store_dwordx4 %0, %1, off sc0 sc1" :: "v"(dst), "v"(v) : "memory");
}
__device__ inline void vm_drain(){
  asm volatile("s_waitcnt vmcnt(0)" ::: "memory");
}

// ---------------- cooperative pipelined scan ----------------
// Role-per-XCD: L0 WGs of group g on XCD 2g, L1 on XCD 2g+1 (16 slices each).
struct ScanP {
  const short* wrec;
  short *pub0, *pub1;
  int *ctrA, *ctrB;
  int cstride;                                   // ints per step-slot
  const float *bh0,*bmup0,*bsgp0,*bh1,*bmup1,*bsgp1,*bout;
  const float *Am0,*As0,*E0,*Am1,*As1,*E1;
  float *out, *klpart;
};

__global__ __launch_bounds__(384, 1) void pvrnn_scan(ScanP P){
  extern __shared__ char smem[];
  short* ldsW  = (short*)smem;                   // up to 82 records * 1024B
  float* muqS  = (float*)(smem + 83968);         // [2][32][64] f32
  float* tqS   = (float*)(smem + 100352);        // [2][32][64] f32
  short* zbS   = (short*)(smem + 116736);        // [2][32][CW] bf16
  short* dtile = (short*)(smem + 124928);        // [32][32] bf16
  float* mupT  = (float*)(smem + 126976);        // [32][4]
  float* tpT   = (float*)(smem + 127488);        // [32][4]
  float* xT    = (float*)(smem + 128000);        // [32][4]

  const int p = blockIdx.x;
  const int xcd = p & 7;
  const int g = xcd >> 1;                         // group on XCD pair (2g, 2g+1)
  const int role = xcd & 1;                       // 0=L0 on even XCD, 1=L1 on odd
  const int s = p >> 3;                           // slice 0..15
  const int wid = g*32 + role*16 + s;

  const int tid = threadIdx.x;
  const int l = tid & 63, w = tid >> 6;           // wave 0..5
  const int m = w & 1, n = w >> 1;                // n: 0,1 rec ; 2 head
  const int c = l & 15, kb8 = (l >> 4) * 8;
  const int rowbase = 32*g + 16*m;
  const int CW = role ? 32 : 64;
  const int sh = role ? 5 : 6;
  const int CS = P.cstride;

  { // weights -> LDS (linear, conflict-free records)
    const u32x4* src = (const u32x4*)(P.wrec + (size_t)(role ? (832 + s*82) : (s*52)) * 512);
    const int n16 = (role ? 82 : 52) * 64;
    for (int i = tid; i < n16; i += 384) ((u32x4*)ldsW)[i] = src[i];
  }
  float bias_rec = 0.f, bias_head = 0.f;
  if (n < 2){
    bias_rec = role ? P.bh1[32*s + 16*n + c] : P.bh0[32*s + 16*n + c];
  } else {
    if (!role){
      if (c < 4)      bias_head = P.bmup0[4*s + c];
      else if (c < 8) bias_head = P.bsgp0[4*s + c - 4];
    } else {
      if (c < 2)      bias_head = P.bmup1[2*s + c];
      else if (c < 4) bias_head = P.bsgp1[2*s + c - 2];
      else if (c < 8) bias_head = P.bout [4*s + c - 4];
    }
  }
  const float* AM = role ? P.Am1 : P.Am0;
  const float* AS = role ? P.As1 : P.As0;
  const float* EP = role ? P.E1  : P.E0;

  auto do_stats = [&](int tt){
    const int par2 = tt & 1;
    const int NE = 32 << sh;
    for (int idx = tid; idx < NE; idx += 384){
      int rr = idx >> sh, cc = idx & (CW - 1);
      size_t sidx = ((size_t)(32*g + rr) * 2048 + tt) * CW + cc;
      float mq = tanhf(AM[sidx]);
      float tq = tanhf(AS[sidx]);
      int o = (par2*32 + rr)*64 + cc;
      muqS[o] = mq; tqS[o] = tq;
      zbS[(par2*32 + rr)*CW + cc] = (short)f2bf(fmaf(__expf(tq), EP[sidx], mq));
    }
  };
  do_stats(0);
  __syncthreads();

  float h[4] = {0.f,0.f,0.f,0.f};
  float klacc = 0.f;
  bool dead = false;
  int* myctr  = (role ? P.ctrB : P.ctrA) + (size_t)g * 2048 * CS;
  int* othctr = (role ? P.ctrA : P.ctrB) + (size_t)g * 2048 * CS;
  const short* pubA = role ? P.pub1 : P.pub0;
  short* pubW = role ? P.pub1 : P.pub0;
  const float leak = role ? 0.875f : 0.5f, gain = role ? 0.125f : 0.5f;

  for (int t = 0; t < 2048; ++t){
    if (tid == 0){
      auto spinw = [&](int* a, int tgt){
        if (dead) return;
        int it = 0;
        while (__hip_atomic_load(a, __ATOMIC_RELAXED, __HIP_MEMORY_SCOPE_AGENT) < tgt){
          __builtin_amdgcn_s_sleep(1);
          if (++it > 2000000){ dead = true; return; }
        }
      };
      if (!role){
        if (t >= 1) spinw(myctr + (size_t)(t-1)*CS, 16);    // own layer chain
        if (t >= 4) spinw(othctr + (size_t)(t-4)*CS, 16);   // ring overwrite safety
      } else {
        spinw(othctr + (size_t)t*CS, 16);                   // d0(t) ready
        if (t >= 1) spinw(myctr + (size_t)(t-1)*CS, 16);    // d1(t-1) ready
      }
    }
    __syncthreads();

    const int par = t & 1;
    const short* A1 = pubA + (size_t)(((t-1)&3)*128 + rowbase) * 512;
    u32x4 af[16], ag[16];
    gld16(af, A1 + c*512 + kb8);
    if (role && n < 2){
      const short* A2 = P.pub0 + (size_t)((t&3)*128 + rowbase) * 512;
      gld16(ag, A2 + c*512 + kb8);
    }
    vm_drain();
    __builtin_amdgcn_sched_barrier(0);

    f32x4 acc = {0.f,0.f,0.f,0.f}, accB = {0.f,0.f,0.f,0.f};
#pragma unroll
    for (int k = 0; k < 16; k += 2){
      short8 b0 = *(const short8*)(ldsW + (n*16 + k  )*512 + l*8);
      short8 b1 = *(const short8*)(ldsW + (n*16 + k+1)*512 + l*8);
      acc  = __builtin_amdgcn_mfma_f32_16x16x32_bf16(*(const short8*)&af[k],   b0, acc,  0,0,0);
      accB = __builtin_amdgcn_mfma_f32_16x16x32_bf16(*(const short8*)&af[k+1], b1, accB, 0,0,0);
    }
    if (n < 2){
      if (role){
#pragma unroll
        for (int k = 0; k < 16; k += 2){
          short8 b0 = *(const short8*)(ldsW + (48 + n*16 + k  )*512 + l*8);
          short8 b1 = *(const short8*)(ldsW + (48 + n*16 + k+1)*512 + l*8);
          acc  = __builtin_amdgcn_mfma_f32_16x16x32_bf16(*(const short8*)&ag[k],   b0, acc,  0,0,0);
          accB = __builtin_amdgcn_mfma_f32_16x16x32_bf16(*(const short8*)&ag[k+1], b1, accB, 0,0,0);
        }
        short8 az = *(const short8*)(zbS + (par*32 + 16*m + c)*32 + kb8);
        short8 bz = *(const short8*)(ldsW + (80 + n)*512 + l*8);
        acc = __builtin_amdgcn_mfma_f32_16x16x32_bf16(az, bz, acc, 0, 0, 0);
      } else {
        short8 az0 = *(const short8*)(zbS + (par*32 + 16*m + c)*64 + kb8);
        short8 az1 = *(const short8*)(zbS + (par*32 + 16*m + c)*64 + 32 + kb8);
        short8 bz0 = *(const short8*)(ldsW + (48 + n*2    )*512 + l*8);
        short8 bz1 = *(const short8*)(ldsW + (48 + n*2 + 1)*512 + l*8);
        acc  = __builtin_amdgcn_mfma_f32_16x16x32_bf16(az0, bz0, acc,  0,0,0);
        accB = __builtin_amdgcn_mfma_f32_16x16x32_bf16(az1, bz1, accB, 0,0,0);
      }
    }
    acc = acc + accB;

    // epilogue
    if (n < 2){
#pragma unroll
      for (int j = 0; j < 4; ++j){
        float pre = acc[j] + bias_rec;
        h[j] = leak*h[j] + gain*pre;
        int row = 16*m + (l>>4)*4 + j;
        dtile[row*32 + 16*n + c] = (short)f2bf(tanhf(h[j]));
      }
    } else {
#pragma unroll
      for (int j = 0; j < 4; ++j){
        float pre = acc[j] + bias_head;
        int row = 16*m + (l>>4)*4 + j;
        if (!role){
          if (c < 4)      mupT[row*4 + c]     = tanhf(pre);
          else if (c < 8) tpT [row*4 + c - 4] = tanhf(pre);
        } else {
          if (c < 2)      mupT[row*4 + c]     = tanhf(pre);
          else if (c < 4) tpT [row*4 + c - 2] = tanhf(pre);
          else if (c < 8) xT  [row*4 + c - 4] = 1.f/(1.f + __expf(-pre));
        }
      }
    }
    __syncthreads();
    if (w < 2){                                   // publish d slice -> LLC
      int row = tid >> 2, qq = tid & 3;
      short* dst = pubW + (size_t)((t&3)*128 + 32*g + row)*512 + 32*s + qq*8;
      llc_store16(dst, *(const u32x4*)(dtile + row*32 + qq*8));
      vm_drain();                                 // committed to LLC before barrier
    } else if (w == 2 && l < 32){
      if (role && t >= 1)
        *(float4*)(P.out + ((size_t)(32*g + l)*2048 + (t-1))*64 + 4*s)
          = *(const float4*)(xT + l*4);
    } else if (w == 4 && l < 32){
      const int CC = role ? 2 : 4;
#pragma unroll
      for (int cc = 0; cc < 4; ++cc){
        if (cc < CC){
          float mp = mupT[l*4 + cc], tp = tpT[l*4 + cc];
          int zc = role ? (2*s + cc) : (4*s + cc);
          float mq = muqS[(par*32 + l)*64 + zc];
          float tq = tqS [(par*32 + l)*64 + zc];
          float dm = mq - mp;
          klacc += tp - tq + (__expf(2.f*tq) + dm*dm)*0.5f*__expf(-2.f*tp) - 0.5f;
        }
      }
    }
    __syncthreads();
    if (tid == 0)
      __hip_atomic_fetch_add(myctr + (size_t)t*CS, 1, __ATOMIC_RELAXED, __HIP_MEMORY_SCOPE_AGENT);
    if (t + 1 < 2048) do_stats(t + 1);            // overlap next-step input stats
  }

  if (role){                                      // final x(2047) from d1(2047)
    if (tid == 0){
      int it = 0;
      while (!dead &&
             __hip_atomic_load(myctr + (size_t)2047*CS, __ATOMIC_RELAXED, __HIP_MEMORY_SCOPE_AGENT) < 16){
        __builtin_amdgcn_s_sleep(1);
        if (++it > 2000000) dead = true;
      }
    }
    __syncthreads();
    if (n == 2){
      const short* A1 = P.pub1 + (size_t)((2047&3)*128 + rowbase) * 512;
      u32x4 af[16];
      gld16(af, A1 + c*512 + kb8);
      vm_drain();
      __builtin_amdgcn_sched_barrier(0);
      f32x4 acc = {0.f,0.f,0.f,0.f};
#pragma unroll
      for (int k = 0; k < 16; ++k){
        short8 bf = *(const short8*)(ldsW + (32 + k)*512 + l*8);
        acc = __builtin_amdgcn_mfma_f32_16x16x32_bf16(*(const short8*)&af[k], bf, acc, 0, 0, 0);
      }
#pragma unroll
      for (int j = 0; j < 4; ++j){
        if (c >= 4 && c < 8){
          int row = 16*m + (l>>4)*4 + j;
          xT[row*4 + c - 4] = 1.f/(1.f + __expf(-(acc[j] + bias_head)));
        }
      }
    }
    __syncthreads();
    if (w == 2 && l < 32)
      *(float4*)(P.out + ((size_t)(32*g + l)*2048 + 2047)*64 + 4*s)
        = *(const float4*)(xT + l*4);
  }

  if (w == 4){
    float v = klacc;
#pragma unroll
    for (int off = 32; off; off >>= 1) v += __shfl_down(v, off);
    if (l == 0) P.klpart[wid] = v;
  }
}

__global__ void kl_finalize(const float* __restrict__ klpart, float* __restrict__ out){
  if (blockIdx.x == 0 && threadIdx.x == 0){
    float k0 = 0.f, k1 = 0.f;
    for (int i = 0; i < 128; ++i){
      if ((i >> 4) & 1) k1 += klpart[i]; else k0 += klpart[i];
    }
    float kl = (k0 + k1) * (1.0f/128.0f);
    out[16777216] = kl;
    out[16777217] = 0.001f * kl;
  }
}

extern "C" void kernel_launch(void* const* d_in, const int* in_sizes, int n_in,
                              void* d_out, int out_size, void* d_ws, size_t ws_size,
                              hipStream_t stream){
  (void)in_sizes; (void)n_in; (void)out_size;
  const float* Wdh0  = (const float*)d_in[0];
  const float* Wzh0  = (const float*)d_in[1];
  const float* bh0   = (const float*)d_in[2];
  const float* Wmup0 = (const float*)d_in[3];
  const float* bmup0 = (const float*)d_in[4];
  const float* Wsgp0 = (const float*)d_in[5];
  const float* bsgp0 = (const float*)d_in[6];
  const float* Amu0  = (const float*)d_in[7];
  const float* Asg0  = (const float*)d_in[8];
  const float* Eps0  = (const float*)d_in[9];
  const float* Wdh1  = (const float*)d_in[10];
  const float* Wzh1  = (const float*)d_in[11];
  const float* Wih1  = (const float*)d_in[12];
  const float* bh1   = (const float*)d_in[13];
  const float* Wmup1 = (const float*)d_in[14];
  const float* bmup1 = (const float*)d_in[15];
  const float* Wsgp1 = (const float*)d_in[16];
  const float* bsgp1 = (const float*)d_in[17];
  const float* Amu1  = (const float*)d_in[18];
  const float* Asg1  = (const float*)d_in[19];
  const float* Eps1  = (const float*)d_in[20];
  const float* Wout  = (const float*)d_in[21];
  const float* bout  = (const float*)d_in[22];

  // counter slot stride (ints): prefer a full cacheline per step
  const size_t oW    = 0;                      // 2144 records * 1024 B
  const size_t oPub0 = 2195456;                // [4][128][512] bf16
  const size_t oPub1 = oPub0 + 524288;
  size_t fixed = oPub1 + 524288;
  int cstride = 16;
  size_t ctrbytes = (size_t)4 * 2048 * cstride * 4;
  if (fixed + 2*ctrbytes + 512 > ws_size){ cstride = 4; ctrbytes = (size_t)4*2048*cstride*4; }
  if (fixed + 2*ctrbytes + 512 > ws_size){ cstride = 1; ctrbytes = (size_t)4*2048*cstride*4; }
  const size_t oCtrA = fixed;
  const size_t oCtrB = oCtrA + ctrbytes;
  const size_t oKL   = oCtrB + ctrbytes;
  const size_t total = oKL + 512;
  if (ws_size < total) return;
  char* ws = (char*)d_ws;

  (void)hipMemsetAsync(ws + oPub0, 0, total - oPub0, stream);  // zero pubs + counters + klpart

  PreP pp;
  pp.Wdh0 = Wdh0; pp.Wzh0 = Wzh0; pp.Wmup0 = Wmup0; pp.Wsgp0 = Wsgp0;
  pp.Wdh1 = Wdh1; pp.Wzh1 = Wzh1; pp.Wih1 = Wih1; pp.Wmup1 = Wmup1;
  pp.Wsgp1 = Wsgp1; pp.Wout = Wout; pp.dst = (uint32_t*)(ws + oW);
  prepack<<<dim3(2144), dim3(64), 0, stream>>>(pp);

  ScanP sp;
  sp.wrec = (const short*)(ws + oW);
  sp.pub0 = (short*)(ws + oPub0);
  sp.pub1 = (short*)(ws + oPub1);
  sp.ctrA = (int*)(ws + oCtrA);
  sp.ctrB = (int*)(ws + oCtrB);
  sp.cstride = cstride;
  sp.bh0 = bh0; sp.bmup0 = bmup0; sp.bsgp0 = bsgp0;
  sp.bh1 = bh1; sp.bmup1 = bmup1; sp.bsgp1 = bsgp1; sp.bout = bout;
  sp.Am0 = Amu0; sp.As0 = Asg0; sp.E0 = Eps0;
  sp.Am1 = Amu1; sp.As1 = Asg1; sp.E1 = Eps1;
  sp.out = (float*)d_out;
  sp.klpart = (float*)(ws + oKL);

  const unsigned SMEM = 128512u;
  (void)hipFuncSetAttribute((const void*)pvrnn_scan,
                            hipFuncAttributeMaxDynamicSharedMemorySize, 131072);
  void* args[] = { &sp };
  if (hipLaunchCooperativeKernel((void*)pvrnn_scan, dim3(128), dim3(384),
                                 args, SMEM, stream) != hipSuccess){
    pvrnn_scan<<<dim3(128), dim3(384), SMEM, stream>>>(sp);
  }
  kl_finalize<<<1, 1, 0, stream>>>((const float*)(ws + oKL), (float*)d_out);
}